// Round 1
// baseline (500.075 us; speedup 1.0000x reference)
//
#include <hip/hip_runtime.h>
#include <cstdint>
#include <cstddef>

// ---------------------------------------------------------------------------
// TokenRoutedMLP on MI355X (gfx950)
// R5: k_gateup/k_down K-loops converted from 2-barrier-per-step (load; sync;
// compute; sync) to single-barrier double-buffered prefetch: issue next
// K-tile's global_load_lds BEFORE computing current tile, one __syncthreads
// (vmcnt(0) drain) per step. LDS 32->64 KB per block (2 blocks/CU).
// Plus bijective XCD-aware block swizzle (1152 = 8*144) so the 16 col-blocks
// sharing one A token-tile land on the same XCD's L2.
// ---------------------------------------------------------------------------

typedef __attribute__((ext_vector_type(8))) _Float16 half8;
typedef __attribute__((ext_vector_type(4))) float floatx4;

#define AS_G __attribute__((address_space(1)))
#define AS_L __attribute__((address_space(3)))

__device__ __forceinline__ void async_cp16(void* lds, const void* g) {
  __builtin_amdgcn_global_load_lds((const AS_G uint32_t*)g, (AS_L uint32_t*)lds,
                                   16, 0, 0);
}

static constexpr int TTOK = 8192;
static constexpr int DIMK = 2048;
static constexpr int EI = 1024;
static constexpr int NE = 8;
static constexpr int PADT = 9216;
static constexpr int MAXTILES = 80;
static constexpr int NTILE_LAUNCH = 72;

// ------------------------------------------------- routing: hist + tiles ---
__global__ __launch_bounds__(256) void k_route(const int* __restrict__ ids,
                                               int* __restrict__ perm,
                                               int* __restrict__ te,
                                               int* __restrict__ tr0,
                                               int* __restrict__ tnr,
                                               int* __restrict__ cur) {
  __shared__ int cnt[NE];
  __shared__ int sstart[NE];
  __shared__ int snpad[NE];
  __shared__ int stotal;
  int tid = threadIdx.x;
  if (tid < NE) cnt[tid] = 0;
  __syncthreads();
  for (int t = tid; t < TTOK; t += 256) atomicAdd(&cnt[ids[t]], 1);
  __syncthreads();
  if (tid == 0) {
    int pr = 0, nt = 0;
    for (int e = 0; e < NE; e++) {
      int n = cnt[e];
      sstart[e] = pr;
      cur[e] = pr;
      int padded = ((n + 127) >> 7) << 7;
      snpad[e] = padded - n;
      for (int j = 0; j < n; j += 128) {
        te[nt] = e; tr0[nt] = pr + j; tnr[nt] = min(128, n - j); nt++;
      }
      pr += padded;
    }
    stotal = pr;
    for (; nt < MAXTILES; nt++) { te[nt] = 0; tr0[nt] = 0; tnr[nt] = 0; }
  }
  __syncthreads();
  // fill the padding slots of perm (within each expert's range) with token 0
  for (int e = 0; e < NE; e++) {
    int base = sstart[e] + cnt[e];
    for (int i = tid; i < snpad[e]; i += 256) perm[base + i] = 0;
  }
  // fill the unused tail [stotal, PADT) too — k_prep's gather reads it
  for (int i = stotal + tid; i < PADT; i += 256) perm[i] = 0;
}

// -------------------------------------------- routing: parallel scatter ----
__global__ __launch_bounds__(256) void k_scatter(const int* __restrict__ ids,
                                                 int* __restrict__ cur,
                                                 int* __restrict__ perm) {
  __shared__ int bcnt[NE], bbase[NE], bloc[NE];
  int tid = threadIdx.x;
  int t = blockIdx.x * 256 + tid;
  if (tid < NE) { bcnt[tid] = 0; bloc[tid] = 0; }
  __syncthreads();
  int e = ids[t];
  atomicAdd(&bcnt[e], 1);
  __syncthreads();
  if (tid < NE && bcnt[tid] > 0) bbase[tid] = atomicAdd(&cur[tid], bcnt[tid]);
  __syncthreads();
  int off = atomicAdd(&bloc[e], 1);
  perm[bbase[e] + off] = t;
}

// ------------------------------------------- transpose tile (64x64) body ---
template <int K, int N>
__device__ __forceinline__ void transpose_tile(const float* __restrict__ src,
                                               _Float16* __restrict__ dst,
                                               float (*tile)[67], int e,
                                               int n0, int k0, int tid) {
  const float* s = src + (size_t)e * K * N;
  _Float16* d = dst + (size_t)e * N * K;
  int kk = tid >> 4;
  int nn = (tid & 15) * 4;
#pragma unroll
  for (int i = 0; i < 4; i++) {
    float4 v = *(const float4*)(s + (size_t)(k0 + kk + i * 16) * N + n0 + nn);
    tile[kk + i * 16][nn + 0] = v.x;
    tile[kk + i * 16][nn + 1] = v.y;
    tile[kk + i * 16][nn + 2] = v.z;
    tile[kk + i * 16][nn + 3] = v.w;
  }
  __syncthreads();
  int nrow = tid >> 3;
  int k8 = (tid & 7) * 8;
#pragma unroll
  for (int i = 0; i < 2; i++) {
    int n = nrow + i * 32;
    half8 o;
#pragma unroll
    for (int j = 0; j < 8; j++) o[j] = (_Float16)tile[k8 + j][n];
    *(half8*)(d + (size_t)(n0 + n) * K + k0 + k8) = o;
  }
}

// ------------------------- fused: gather x->f16  +  gate_up transpose ------
__global__ __launch_bounds__(256) void k_prep(const float* __restrict__ gup,
                                              _Float16* __restrict__ wt1,
                                              const float* __restrict__ x,
                                              const int* __restrict__ perm,
                                              _Float16* __restrict__ xg) {
  __shared__ float tile[64][67];
  int b = blockIdx.x;
  int tid = threadIdx.x;
  if (b < 8192) {
    int e = b >> 10;
    int r = b & 1023;
    transpose_tile<DIMK, DIMK>(gup, wt1, tile, e, (r & 31) * 64, (r >> 5) * 64,
                               tid);
  } else {
    int row = b - 8192;
    int tok = perm[row];
    int c = tid * 8;
    const float* s = x + (size_t)tok * DIMK + c;
    float4 a = *(const float4*)s;
    float4 bb = *(const float4*)(s + 4);
    half8 o;
    o[0] = (_Float16)a.x; o[1] = (_Float16)a.y;
    o[2] = (_Float16)a.z; o[3] = (_Float16)a.w;
    o[4] = (_Float16)bb.x; o[5] = (_Float16)bb.y;
    o[6] = (_Float16)bb.z; o[7] = (_Float16)bb.w;
    *(half8*)(xg + (size_t)row * DIMK + c) = o;
  }
}

// --------------------------------------------- down-proj transpose ---------
__global__ __launch_bounds__(256) void k_t2(const float* __restrict__ dwn,
                                            _Float16* __restrict__ wt2) {
  __shared__ float tile[64][67];
  transpose_tile<EI, DIMK>(dwn, wt2, tile, blockIdx.z, blockIdx.x * 64,
                           blockIdx.y * 64, threadIdx.x);
}

// --------------------------------------------------------- layer 1 (g,u) ---
// per block: 128 tokens x (64 gate + 64 up cols), K=2048, BK=64.
// Double-buffered LDS; prefetch next K-tile before computing current; one
// __syncthreads (vmcnt(0)+lgkmcnt(0)+barrier) per K-step.
__global__ __launch_bounds__(256) void k_gateup(
    const _Float16* __restrict__ xg, const _Float16* __restrict__ wt1,
    const int* __restrict__ te, const int* __restrict__ tr0,
    const int* __restrict__ tnr, _Float16* __restrict__ hbuf) {
  // bijective XCD swizzle: nwg = 16*72 = 1152 = 8*144; consecutive flat ids
  // round-robin across XCDs, so give XCD x the contiguous work chunk
  // [x*144, (x+1)*144) -> the 16 col-blocks sharing an A tile stay on one XCD.
  int flat = blockIdx.y * 16 + blockIdx.x;
  int swz = (flat & 7) * (NTILE_LAUNCH * 16 / 8) + (flat >> 3);
  int tile = swz >> 4;
  int nr = tnr[tile];
  if (nr == 0) return;
  int e = te[tile], r0 = tr0[tile];
  int col = (swz & 15) * 64;
  int tid = threadIdx.x;

  __shared__ __align__(16) _Float16 As[2][128 * 64];  // per buf: 2 slabs [128][32]
  __shared__ __align__(16) _Float16 Bg[2][64 * 64];
  __shared__ __align__(16) _Float16 Bu[2][64 * 64];

  int an = tid >> 2;
  int aq = (tid & 3) ^ ((tid >> 3) & 3);
  const _Float16* ap0 = xg + (size_t)(r0 + an) * DIMK + aq * 8;
  const _Float16* ap1 = ap0 + (size_t)64 * DIMK;
  const _Float16* bgp =
      wt1 + (size_t)e * DIMK * DIMK + (size_t)(col + an) * DIMK + aq * 8;
  const _Float16* bup = bgp + (size_t)EI * DIMK;

  int wave = tid >> 6, lane = tid & 63;
  int wm = (wave & 1) * 64, wn = (wave >> 1) * 32;
  int lm = lane & 15, lq = lane >> 4;
  int aoff[4], boff[2];
#pragma unroll
  for (int i = 0; i < 4; i++) {
    int r = wm + i * 16 + lm;
    aoff[i] = (r * 4 + (lq ^ ((r >> 1) & 3))) * 8;
  }
#pragma unroll
  for (int j = 0; j < 2; j++) {
    int n = wn + j * 16 + lm;
    boff[j] = (n * 4 + (lq ^ ((n >> 1) & 3))) * 8;
  }

  floatx4 accg[4][2], accu[4][2];
#pragma unroll
  for (int i = 0; i < 4; i++)
#pragma unroll
    for (int j = 0; j < 2; j++) {
      accg[i][j] = (floatx4)0.0f;
      accu[i][j] = (floatx4)0.0f;
    }

  auto stage = [&](int p, int k0) {
    _Float16* a = As[p] + (size_t)tid * 8;
    _Float16* g = Bg[p] + (size_t)tid * 8;
    _Float16* u = Bu[p] + (size_t)tid * 8;
    async_cp16(a, ap0 + k0);
    async_cp16(a + 2048, ap1 + k0);
    async_cp16(g, bgp + k0);
    async_cp16(u, bup + k0);
    async_cp16(a + 4096, ap0 + k0 + 32);
    async_cp16(a + 6144, ap1 + k0 + 32);
    async_cp16(g + 2048, bgp + k0 + 32);
    async_cp16(u + 2048, bup + k0 + 32);
  };

  stage(0, 0);
  __syncthreads();  // vmcnt(0): buffer 0 ready

  int p = 0;
  for (int k0 = 0; k0 < DIMK; k0 += 64, p ^= 1) {
    if (k0 + 64 < DIMK) stage(p ^ 1, k0 + 64);  // prefetch next K-tile
#pragma unroll
    for (int s = 0; s < 2; s++) {
      const _Float16* Ab = As[p] + s * 4096;
      const _Float16* Bgb = Bg[p] + s * 2048;
      const _Float16* Bub = Bu[p] + s * 2048;
      half8 af[4], bgf[2], buf_[2];
#pragma unroll
      for (int i = 0; i < 4; i++) af[i] = *(const half8*)(Ab + aoff[i]);
#pragma unroll
      for (int j = 0; j < 2; j++) {
        bgf[j] = *(const half8*)(Bgb + boff[j]);
        buf_[j] = *(const half8*)(Bub + boff[j]);
      }
#pragma unroll
      for (int i = 0; i < 4; i++)
#pragma unroll
        for (int j = 0; j < 2; j++) {
          accg[i][j] = __builtin_amdgcn_mfma_f32_16x16x32_f16(
              af[i], bgf[j], accg[i][j], 0, 0, 0);
          accu[i][j] = __builtin_amdgcn_mfma_f32_16x16x32_f16(
              af[i], buf_[j], accu[i][j], 0, 0, 0);
        }
    }
    // one barrier per K-step: drains the prefetch (vmcnt(0)) issued above —
    // its latency overlapped with this step's 32 MFMA — and protects the
    // just-consumed buffer before next iteration's stage overwrites it.
    __syncthreads();
  }

#pragma unroll
  for (int i = 0; i < 4; i++) {
    int rbase = wm + i * 16 + lq * 4;
#pragma unroll
    for (int j = 0; j < 2; j++) {
      int c = col + wn + j * 16 + lm;
#pragma unroll
      for (int rr = 0; rr < 4; rr++) {
        float g = accg[i][j][rr];
        float u = accu[i][j][rr];
        float h = g / (1.0f + __expf(-g)) * u;
        hbuf[(size_t)(r0 + rbase + rr) * EI + c] = (_Float16)h;
      }
    }
  }
}

// ------------------------------------------------------------- layer 2 -----
// per block: 128 tokens x 128 out cols, K=1024, BK=64. Same dbuf pipeline.
__global__ __launch_bounds__(256) void k_down(
    const _Float16* __restrict__ hbuf, const _Float16* __restrict__ wt2,
    const int* __restrict__ perm, const int* __restrict__ te,
    const int* __restrict__ tr0, const int* __restrict__ tnr,
    float* __restrict__ out) {
  int flat = blockIdx.y * 16 + blockIdx.x;
  int swz = (flat & 7) * (NTILE_LAUNCH * 16 / 8) + (flat >> 3);
  int tile = swz >> 4;
  int nr = tnr[tile];
  if (nr == 0) return;
  int e = te[tile], r0 = tr0[tile];
  int col = (swz & 15) * 128;
  int tid = threadIdx.x;

  __shared__ __align__(16) _Float16 As[2][128 * 64];
  __shared__ __align__(16) _Float16 Bs[2][128 * 64];

  int an = tid >> 2;
  int aq = (tid & 3) ^ ((tid >> 3) & 3);
  const _Float16* ap0 = hbuf + (size_t)(r0 + an) * EI + aq * 8;
  const _Float16* ap1 = ap0 + (size_t)64 * EI;
  const _Float16* wte = wt2 + (size_t)e * DIMK * EI;
  const _Float16* bp0 = wte + (size_t)(col + an) * EI + aq * 8;
  const _Float16* bp1 = bp0 + (size_t)64 * EI;

  int wave = tid >> 6, lane = tid & 63;
  int wm = (wave & 1) * 64, wn = (wave >> 1) * 64;
  int lm = lane & 15, lq = lane >> 4;
  int aoff[4], boff[4];
#pragma unroll
  for (int i = 0; i < 4; i++) {
    int r = wm + i * 16 + lm;
    aoff[i] = (r * 4 + (lq ^ ((r >> 1) & 3))) * 8;
    int n = wn + i * 16 + lm;
    boff[i] = (n * 4 + (lq ^ ((n >> 1) & 3))) * 8;
  }

  floatx4 acc[4][4];
#pragma unroll
  for (int i = 0; i < 4; i++)
#pragma unroll
    for (int j = 0; j < 4; j++) acc[i][j] = (floatx4)0.0f;

  auto stage = [&](int p, int k0) {
    _Float16* a = As[p] + (size_t)tid * 8;
    _Float16* b = Bs[p] + (size_t)tid * 8;
    async_cp16(a, ap0 + k0);
    async_cp16(a + 2048, ap1 + k0);
    async_cp16(b, bp0 + k0);
    async_cp16(b + 2048, bp1 + k0);
    async_cp16(a + 4096, ap0 + k0 + 32);
    async_cp16(a + 6144, ap1 + k0 + 32);
    async_cp16(b + 4096, bp0 + k0 + 32);
    async_cp16(b + 6144, bp1 + k0 + 32);
  };

  stage(0, 0);
  __syncthreads();

  int p = 0;
  for (int k0 = 0; k0 < EI; k0 += 64, p ^= 1) {
    if (k0 + 64 < EI) stage(p ^ 1, k0 + 64);
#pragma unroll
    for (int s = 0; s < 2; s++) {
      const _Float16* Ab = As[p] + s * 4096;
      const _Float16* Bb = Bs[p] + s * 4096;
      half8 af[4], bf[4];
#pragma unroll
      for (int i = 0; i < 4; i++) {
        af[i] = *(const half8*)(Ab + aoff[i]);
        bf[i] = *(const half8*)(Bb + boff[i]);
      }
#pragma unroll
      for (int i = 0; i < 4; i++)
#pragma unroll
        for (int j = 0; j < 4; j++)
          acc[i][j] = __builtin_amdgcn_mfma_f32_16x16x32_f16(af[i], bf[j],
                                                             acc[i][j], 0, 0, 0);
    }
    __syncthreads();
  }

#pragma unroll
  for (int i = 0; i < 4; i++) {
    int rbase = wm + i * 16 + lq * 4;
#pragma unroll
    for (int rr = 0; rr < 4; rr++) {
      int r = rbase + rr;
      if (r < nr) {
        int tok = perm[r0 + r];
        float* orow = out + (size_t)tok * DIMK + col;
#pragma unroll
        for (int j = 0; j < 4; j++) orow[wn + j * 16 + lm] = acc[i][j][rr];
      }
    }
  }
}

// ---------------------------------------------------------------- launch ---
extern "C" void kernel_launch(void* const* d_in, const int* in_sizes, int n_in,
                              void* d_out, int out_size, void* d_ws,
                              size_t ws_size, hipStream_t stream) {
  const float* x = (const float*)d_in[0];
  const int* ids = (const int*)d_in[1];
  const float* gup = (const float*)d_in[2];
  const float* dwn = (const float*)d_in[3];
  float* out = (float*)d_out;
  char* ws = (char*)d_ws;

  int* perm = (int*)ws;                          // 9216 ints
  int* te = (int*)(ws + 36864);
  int* tr0 = (int*)(ws + 36864 + 512);
  int* tnr = (int*)(ws + 36864 + 1024);
  int* cur = (int*)(ws + 36864 + 1536);          // 8 ints
  _Float16* wt1 = (_Float16*)(ws + 65536);                  // 67,108,864 B
  _Float16* hbuf = (_Float16*)(ws + 65536 + 67108864);      // 18,874,368 B
  _Float16* xg = (_Float16*)(ws + 65536 + 67108864 + 18874368);  // 37,748,736 B
  _Float16* wt2 = wt1;  // aliased; k_t2 runs after k_gateup is done with wt1
  // peak ws = 123,797,504 B

  k_route<<<dim3(1), dim3(256), 0, stream>>>(ids, perm, te, tr0, tnr, cur);
  k_scatter<<<dim3(32), dim3(256), 0, stream>>>(ids, cur, perm);
  k_prep<<<dim3(8192 + PADT), dim3(256), 0, stream>>>(gup, wt1, x, perm, xg);
  k_gateup<<<dim3(16, NTILE_LAUNCH), dim3(256), 0, stream>>>(
      xg, wt1, te, tr0, tnr, hbuf);
  k_t2<<<dim3(32, 16, 8), dim3(256), 0, stream>>>(dwn, wt2);
  k_down<<<dim3(16, NTILE_LAUNCH), dim3(256), 0, stream>>>(
      hbuf, wt2, perm, te, tr0, tnr, out);
}